// Round 6
// baseline (68.372 us; speedup 1.0000x reference)
//
#include <hip/hip_runtime.h>

#define BB 32
#define CC 1024
#define QQ 128
#define EE 512

typedef unsigned int uint32;
typedef unsigned short u16;
typedef __bf16 bf16x8 __attribute__((ext_vector_type(8)));
typedef float f32x4 __attribute__((ext_vector_type(4)));

// workspace layout (bytes)
#define QMF_OFF  (0u)                  // bf16 frag-major: [b][ks 0..15][nf 0..7][lane][8]  (qm' = q*ws_m + ws_c)
#define QTF_OFF  (4u<<20)              // bf16 frag-major: [b][ks2 0..3][ne 0..31][lane][8]
#define PV_OFF   (8u<<20)              // f32 [b][64 groups][512]
#define QD_OFF   (12u<<20)             // f32 [b][128]
#define MT_OFF   ((12u<<20) + 16384u)  // f32 [b][64]
#define ST_OFF   (MT_OFF + 8192u)      // f32 [b][64]

__device__ __forceinline__ u16 bfc(float f){
  __bf16 h = (__bf16)f;                // HW v_cvt (RNE)
  return __builtin_bit_cast(u16, h);
}

// ---- prep: qmf = bf16(q*ws_m + ws_c) in GEMM1 B-fragment-major layout ----
__global__ __launch_bounds__(256) void k_prep_qm(const float* __restrict__ q,
                                                 const float* __restrict__ ws,
                                                 unsigned char* __restrict__ wsp){
  const int b = blockIdx.x >> 2, et = blockIdx.x & 3, e0 = et*128;
  __shared__ u16 tile[128*136];
  const int tid = threadIdx.x;
  #pragma unroll
  for (int i=0;i<16;i++){
    int id = tid + i*256;
    int qi = id >> 5;
    int el = (id & 31) << 2;
    float4 v = *(const float4*)(q + (size_t)(b*QQ+qi)*EE + e0 + el);
    float4 m = *(const float4*)(ws + 2*EE + e0 + el);
    float4 c = *(const float4*)(ws +   EE + e0 + el);
    ushort4 u; u.x = bfc(v.x*m.x + c.x); u.y = bfc(v.y*m.y + c.y);
               u.z = bfc(v.z*m.z + c.z); u.w = bfc(v.w*m.w + c.w);
    *(ushort4*)&tile[qi*136 + el] = u;
  }
  __syncthreads();
  const int lane = tid & 63, wv = tid >> 6, l15 = lane & 15, l4 = lane >> 4;
  uint4* qmf = (uint4*)(wsp + QMF_OFF);
  #pragma unroll
  for (int i=0;i<8;i++){
    int f = wv*8 + i;
    int kl = f >> 3, nf = f & 7;
    uint4 u = *(const uint4*)&tile[(nf*16 + l15)*136 + kl*32 + l4*8];
    qmf[(size_t)((b*16 + et*4 + kl)*8 + nf)*64 + lane] = u;
  }
}

// ---- prep: qtf = bf16(q) in GEMM2 B-fragment-major layout ----
__global__ __launch_bounds__(256) void k_prep_qt(const float* __restrict__ q,
                                                 unsigned char* __restrict__ wsp){
  const int b = blockIdx.x >> 2, et = blockIdx.x & 3, e0 = et*128;
  __shared__ u16 tile[128*136];
  const int tid = threadIdx.x;
  #pragma unroll
  for (int i=0;i<16;i++){
    int id = tid + i*256;
    int qi = id >> 5;
    int el = (id & 31) << 2;
    float4 v = *(const float4*)(q + (size_t)(b*QQ+qi)*EE + e0 + el);
    ushort4 u; u.x = bfc(v.x); u.y = bfc(v.y); u.z = bfc(v.z); u.w = bfc(v.w);
    *(ushort4*)&tile[qi*136 + el] = u;
  }
  __syncthreads();
  const int lane = tid & 63, wv = tid >> 6, l15 = lane & 15, l4 = lane >> 4;
  uint4* qtf = (uint4*)(wsp + QTF_OFF);
  #pragma unroll
  for (int i=0;i<8;i++){
    int f = wv*8 + i;
    int ks2 = f >> 3, nl = f & 7, ne = et*8 + nl;
    uint32 x[4];
    #pragma unroll
    for (int p=0;p<4;p++){
      u16 t0 = tile[(ks2*32 + l4*8 + 2*p    )*136 + nl*16 + l15];
      u16 t1 = tile[(ks2*32 + l4*8 + 2*p + 1)*136 + nl*16 + l15];
      x[p] = (uint32)t0 | ((uint32)t1 << 16);
    }
    uint4 u; u.x = x[0]; u.y = x[1]; u.z = x[2]; u.w = x[3];
    qtf[(size_t)((b*4 + ks2)*32 + ne)*64 + lane] = u;
  }
}

// ---- prep: qdot[row] = q[row] . ws_q (exact f32) ----
__global__ __launch_bounds__(256) void k_prep_qd(const float* __restrict__ q,
                                                 const float* __restrict__ ws,
                                                 unsigned char* __restrict__ wsp){
  const int row = blockIdx.x*4 + (threadIdx.x >> 6);
  const int lane = threadIdx.x & 63;
  const float4* qr = (const float4*)(q + (size_t)row*EE) + lane*2;
  const float4* wq = (const float4*)ws + lane*2;
  float4 v0 = qr[0], v1 = qr[1], a0 = wq[0], a1 = wq[1];
  float dot = v0.x*a0.x + v0.y*a0.y + v0.z*a0.z + v0.w*a0.w
            + v1.x*a1.x + v1.y*a1.y + v1.z*a1.z + v1.w*a1.w;
  #pragma unroll
  for (int off=1; off<64; off<<=1) dot += __shfl_xor(dot, off);
  if (lane == 0) ((float*)(wsp + QD_OFF))[row] = dot;
}

// ---- main: 1024 blocks x 4 waves; block = 32 ctx rows; wave = 16 rows x q/e-half.
// Single full-K bf16 A-tile stage (reg-staged, MLP-16), ONE barrier, then
// barrier-free GEMM loops with register-level B prefetch (depth 2 / depth 1).
__global__ __launch_bounds__(256, 4) void k_main(const float* __restrict__ ctx,
                                                 unsigned char* __restrict__ wsp,
                                                 float* __restrict__ out){
  __shared__ __align__(16) unsigned char Ast[32*1024];  // bf16 A-tile [32 rows][512], XOR-swizzled; first 8KB later = pfrag
  __shared__ float smax_s[2][2][16];
  __shared__ float ssum_s[2][2][16];
  __shared__ float wrow_s[2][2][16];

  const int bid = blockIdx.x;
  const int sw  = (bid & 7)*128 + (bid >> 3);  // XCD-contiguous (1024%8==0)
  const int b   = sw >> 5;
  const int t   = sw & 31;
  const int tid = threadIdx.x;
  const int lane = tid & 63;
  const int w    = tid >> 6;
  const int rg   = w >> 1;
  const int h    = w & 1;
  const int l15  = lane & 15;
  const int l4   = lane >> 4;
  const int r0   = t*32 + rg*16;

  // qdot for this wave's q-cols (issued first; completes before A-loads drain)
  const float* qdp = (const float*)(wsp + QD_OFF) + b*QQ + h*64 + l15;
  float qd[4];
  #pragma unroll
  for (int n=0;n<4;n++) qd[n] = qdp[n*16];

  // ---- phase 1: whole A-tile to registers (16 float4/lane in flight) ----
  const int srow = w*8 + (lane >> 3);          // 0..31
  const int scol = (lane & 7)*64;              // float index; lane owns 256B of the row
  const float4* src = (const float4*)(ctx + (size_t)(b*CC + t*32 + srow)*EE + scol);
  float4 v[16];
  #pragma unroll
  for (int j=0;j<16;j++) v[j] = src[j];

  // ---- phase 2: convert to bf16, one ds_write pass (XOR-swizzled on 16B slots) ----
  {
    unsigned char* drow = Ast + srow*1024;
    const int dswz = (srow & 7) << 4;
    #pragma unroll
    for (int i=0;i<8;i++){
      float4 x = v[2*i], y = v[2*i+1];
      uint4 u;
      u.x = (uint32)bfc(x.x) | ((uint32)bfc(x.y) << 16);
      u.y = (uint32)bfc(x.z) | ((uint32)bfc(x.w) << 16);
      u.z = (uint32)bfc(y.x) | ((uint32)bfc(y.y) << 16);
      u.w = (uint32)bfc(y.z) | ((uint32)bfc(y.w) << 16);
      *(uint4*)(drow + ((((lane & 7)*128) + i*16) ^ dswz)) = u;
    }
  }
  __syncthreads();                             // barrier 0: tile ready

  // ---- GEMM1: sim[16][64] = A(LDS) . qm'^T, 16 K-steps, depth-2 B prefetch ----
  const int arow = rg*16 + l15;
  const unsigned char* ap = Ast + arow*1024;
  const int a7 = (arow & 7) << 4;
  const uint4* qmf = (const uint4*)(wsp + QMF_OFF) + (size_t)b*8192 + h*256 + lane;

  f32x4 acc[4];
  #pragma unroll
  for (int n=0;n<4;n++) acc[n] = (f32x4){0.f,0.f,0.f,0.f};

  bf16x8 afc = __builtin_bit_cast(bf16x8, *(const uint4*)(ap + ((0*64 + l4*16) ^ a7)));
  uint4 bq0[4], bq1[4];
  #pragma unroll
  for (int n=0;n<4;n++) bq0[n] = qmf[(0*8 + n)*64];
  #pragma unroll
  for (int n=0;n<4;n++) bq1[n] = qmf[(1*8 + n)*64];

  #pragma unroll
  for (int ks=0; ks<16; ks++){
    bf16x8 afn;
    if (ks < 15)
      afn = __builtin_bit_cast(bf16x8, *(const uint4*)(ap + (((ks+1)*64 + l4*16) ^ a7)));
    uint4 bqn[4];
    if (ks < 14){
      #pragma unroll
      for (int n=0;n<4;n++) bqn[n] = qmf[((ks+2)*8 + n)*64];
    }
    #pragma unroll
    for (int n=0;n<4;n++)
      acc[n] = __builtin_amdgcn_mfma_f32_16x16x32_bf16(afc, __builtin_bit_cast(bf16x8, bq0[n]), acc[n], 0, 0, 0);
    afc = afn;
    #pragma unroll
    for (int n=0;n<4;n++){ bq0[n] = bq1[n]; bq1[n] = bqn[n]; }
  }

  // ---- softmax (q-half): v = sim + qdot; half-row max -> LDS ----
  float mxh[4];
  #pragma unroll
  for (int r=0;r<4;r++){
    float m = -3.0e38f;
    #pragma unroll
    for (int n=0;n<4;n++){
      float vv = acc[n][r] + qd[n];
      acc[n][r] = vv;
      m = fmaxf(m, vv);
    }
    m = fmaxf(m, __shfl_xor(m,1));
    m = fmaxf(m, __shfl_xor(m,2));
    m = fmaxf(m, __shfl_xor(m,4));
    m = fmaxf(m, __shfl_xor(m,8));
    mxh[r] = m;
  }
  if (l15 == 0){
    #pragma unroll
    for (int r=0;r<4;r++) smax_s[rg][h][l4*4 + r] = mxh[r];
  }
  __syncthreads();                             // barrier 1: max exchange; all tile reads done
  float mx[4];
  #pragma unroll
  for (int r=0;r<4;r++) mx[r] = fmaxf(smax_s[rg][0][l4*4+r], smax_s[rg][1][l4*4+r]);

  // exp; write P into pfrag (GEMM2 A-frag layout, overlays Ast[0..8KB)); half-sums
  u16* pfr = (u16*)Ast;                        // [rg*4 + ks2][512] u16 = 8KB
  const int l4p = l15 >> 3;
  const int jj  = l15 & 7;
  #pragma unroll
  for (int r=0;r<4;r++){
    float s = 0.f;
    #pragma unroll
    for (int n=0;n<4;n++){
      float p = __expf(acc[n][r] - mx[r]);
      __bf16 hb = (__bf16)p;
      s += (float)hb;
      pfr[(rg*4 + (h<<1) + (n>>1))*512 + ((((n&1)<<1)|l4p)*16 + l4*4 + r)*8 + jj] = __builtin_bit_cast(u16, hb);
    }
    s += __shfl_xor(s,1); s += __shfl_xor(s,2); s += __shfl_xor(s,4); s += __shfl_xor(s,8);
    if (l15 == 0) ssum_s[rg][h][l4*4 + r] = s;
  }

  // q2c stats for this 16-row group (wave-local)
  float m16 = fmaxf(fmaxf(mx[0],mx[1]), fmaxf(mx[2],mx[3]));
  m16 = fmaxf(m16, __shfl_xor(m16,16));
  m16 = fmaxf(m16, __shfl_xor(m16,32));
  float wr[4], s16 = 0.f;
  #pragma unroll
  for (int r=0;r<4;r++){ wr[r] = __expf(mx[r] - m16); s16 += wr[r]; }
  s16 += __shfl_xor(s16,16);
  s16 += __shfl_xor(s16,32);
  if (l15 == 0){
    #pragma unroll
    for (int r=0;r<4;r++) wrow_s[rg][h][l4*4 + r] = wr[r];
  }
  if (h == 0 && lane == 0){
    ((float*)(wsp + MT_OFF))[b*64 + t*2 + rg] = m16;
    ((float*)(wsp + ST_OFF))[b*64 + t*2 + rg] = s16;
  }
  __syncthreads();                             // barrier 2: P + sums exchanged
  float rden[4];
  #pragma unroll
  for (int r=0;r<4;r++) rden[r] = 1.f/(ssum_s[rg][0][l4*4+r] + ssum_s[rg][1][l4*4+r]);

  // ---- GEMM2: c2q rows r0..+15, e-half h; A-frags cached in regs, depth-1 B prefetch ----
  const uint4* qt4 = (const uint4*)(wsp + QTF_OFF) + (size_t)b*8192 + lane;
  const uint4* pf  = (const uint4*)(Ast + rg*4096);
  bf16x8 pa[4];
  #pragma unroll
  for (int ks2=0; ks2<4; ks2++) pa[ks2] = __builtin_bit_cast(bf16x8, pf[ks2*64 + lane]);
  float* ob = out + (size_t)(b*CC + r0)*EE + h*256;

  #pragma unroll
  for (int pp=0; pp<2; pp++){
    const int ne0 = h*16 + pp*8;
    f32x4 acc2[8];
    #pragma unroll
    for (int n2=0;n2<8;n2++) acc2[n2] = (f32x4){0.f,0.f,0.f,0.f};
    uint4 bqc[4];
    #pragma unroll
    for (int n=0;n<4;n++) bqc[n] = qt4[(0*32 + ne0 + n)*64];
    #pragma unroll
    for (int u=0; u<8; u++){                   // u = ks2*2 + half-quad
      const int ks2 = u >> 1, hf = u & 1;
      uint4 bqn[4];
      if (u < 7){
        const int u2 = u + 1;
        #pragma unroll
        for (int n=0;n<4;n++) bqn[n] = qt4[((u2>>1)*32 + ne0 + (u2&1)*4 + n)*64];
      }
      #pragma unroll
      for (int n=0;n<4;n++)
        acc2[hf*4+n] = __builtin_amdgcn_mfma_f32_16x16x32_bf16(pa[ks2], __builtin_bit_cast(bf16x8, bqc[n]), acc2[hf*4+n], 0, 0, 0);
      #pragma unroll
      for (int n=0;n<4;n++) bqc[n] = bqn[n];
    }
    #pragma unroll
    for (int n2=0;n2<8;n2++){
      #pragma unroll
      for (int r=0;r<4;r++)
        ob[(size_t)(l4*4 + r)*EE + pp*128 + n2*16 + l15] = acc2[n2][r]*rden[r];
    }
  }

  // ---- fused q2c partial: rows r0..+15 x e-half h (L2/L3-hot re-read) ----
  {
    const float4* cb = (const float4*)(ctx + (size_t)(b*CC + r0)*EE + h*256) + lane;
    float4 a4; a4.x = 0.f; a4.y = 0.f; a4.z = 0.f; a4.w = 0.f;
    #pragma unroll
    for (int rr=0; rr<16; rr++){
      float wv = wrow_s[rg][h][rr];
      float4 g = cb[(size_t)rr*128];
      a4.x = fmaf(wv, g.x, a4.x); a4.y = fmaf(wv, g.y, a4.y);
      a4.z = fmaf(wv, g.z, a4.z); a4.w = fmaf(wv, g.w, a4.w);
    }
    float* pv = (float*)(wsp + PV_OFF) + (size_t)(b*64 + t*2 + rg)*EE + h*256 + lane*4;
    *(float4*)pv = a4;
  }
}

// ---- q2c combine: 64 group-partials per batch ----
__global__ __launch_bounds__(256) void k_fin(unsigned char* __restrict__ wsp,
                                             float* __restrict__ out){
  const int b = blockIdx.x;
  __shared__ float sc_s[64];
  const int tid = threadIdx.x;
  if (tid < 64){
    float Mg = ((const float*)(wsp + MT_OFF))[b*64 + tid];
    float Sg = ((const float*)(wsp + ST_OFF))[b*64 + tid];
    float M = Mg;
    #pragma unroll
    for (int off=1; off<64; off<<=1) M = fmaxf(M, __shfl_xor(M, off));
    float ev = __expf(Mg - M);
    float ds = ev * Sg;
    #pragma unroll
    for (int off=1; off<64; off<<=1) ds += __shfl_xor(ds, off);
    sc_s[tid] = ev / ds;
  }
  __syncthreads();
  const float* pv = (const float*)(wsp + PV_OFF) + (size_t)b*64*EE;
  float a0 = 0.f, a1 = 0.f;
  #pragma unroll 8
  for (int g=0; g<64; g++){
    float s = sc_s[g];
    a0 = fmaf(s, pv[g*EE + tid],       a0);
    a1 = fmaf(s, pv[g*EE + tid + 256], a1);
  }
  size_t base = (size_t)BB*CC*EE + (size_t)b*EE;
  out[base + tid]       = a0;
  out[base + tid + 256] = a1;
}

extern "C" void kernel_launch(void* const* d_in, const int* in_sizes, int n_in,
                              void* d_out, int out_size, void* d_ws, size_t ws_size,
                              hipStream_t stream){
  const float* ctx = (const float*)d_in[0];
  const float* q   = (const float*)d_in[1];
  const float* ws  = (const float*)d_in[2];
  float* out = (float*)d_out;
  unsigned char* wsp = (unsigned char*)d_ws;

  k_prep_qm<<<dim3(BB*4),    dim3(256), 0, stream>>>(q, ws, wsp);
  k_prep_qt<<<dim3(BB*4),    dim3(256), 0, stream>>>(q, wsp);
  k_prep_qd<<<dim3(BB*QQ/4), dim3(256), 0, stream>>>(q, ws, wsp);
  k_main   <<<dim3(1024),    dim3(256), 0, stream>>>(ctx, wsp, out);
  k_fin    <<<dim3(BB),      dim3(256), 0, stream>>>(wsp, out);
}

// Round 7
// 58.581 us; speedup vs baseline: 1.1671x; 1.1671x over previous
//
#include <hip/hip_runtime.h>

#define BB 32
#define CC 1024
#define QQ 128
#define EE 512

typedef unsigned int uint32;
typedef unsigned short u16;
typedef __bf16 bf16x8 __attribute__((ext_vector_type(8)));
typedef float f32x4 __attribute__((ext_vector_type(4)));

// workspace layout (bytes)
#define QMF_OFF  (0u)                  // bf16 frag-major: [b][ks 0..15][nf 0..7][lane][8]  (qm' = q*ws_m + ws_c)
#define QTF_OFF  (4u<<20)              // bf16 frag-major: [b][ks2 0..3][ne 0..31][lane][8]
#define PV_OFF   (8u<<20)              // f32 [b][64 groups][512]
#define QD_OFF   (12u<<20)             // f32 [b][128]
#define MT_OFF   ((12u<<20) + 16384u)  // f32 [b][64]
#define ST_OFF   (MT_OFF + 8192u)      // f32 [b][64]

__device__ __forceinline__ u16 bfc(float f){
  __bf16 h = (__bf16)f;                // HW v_cvt (RNE)
  return __builtin_bit_cast(u16, h);
}
__device__ __forceinline__ float bf2f(uint32 lo16){
  return __builtin_bit_cast(float, lo16 << 16);
}

// ---- prep: qmf = bf16(q*ws_m + ws_c) in MFMA fragment-major layout ----
// frag (b,ks,nf): value[lane][j] = qm'[nf*16 + (lane&15)][ks*32 + (lane>>4)*8 + j]
__global__ __launch_bounds__(256) void k_prep_qm(const float* __restrict__ q,
                                                 const float* __restrict__ ws,
                                                 unsigned char* __restrict__ wsp){
  const int b = blockIdx.x >> 2, et = blockIdx.x & 3, e0 = et*128;
  __shared__ u16 tile[128*136];
  const int tid = threadIdx.x;
  #pragma unroll
  for (int i=0;i<16;i++){
    int id = tid + i*256;
    int qi = id >> 5;
    int el = (id & 31) << 2;
    float4 v = *(const float4*)(q + (size_t)(b*QQ+qi)*EE + e0 + el);
    float4 m = *(const float4*)(ws + 2*EE + e0 + el);
    float4 c = *(const float4*)(ws +   EE + e0 + el);
    ushort4 u; u.x = bfc(v.x*m.x + c.x); u.y = bfc(v.y*m.y + c.y);
               u.z = bfc(v.z*m.z + c.z); u.w = bfc(v.w*m.w + c.w);
    *(ushort4*)&tile[qi*136 + el] = u;
  }
  __syncthreads();
  const int lane = tid & 63, wv = tid >> 6, l15 = lane & 15, l4 = lane >> 4;
  uint4* qmf = (uint4*)(wsp + QMF_OFF);
  #pragma unroll
  for (int i=0;i<8;i++){
    int f = wv*8 + i;
    int kl = f >> 3, nf = f & 7;
    uint4 u = *(const uint4*)&tile[(nf*16 + l15)*136 + kl*32 + l4*8];
    qmf[(size_t)((b*16 + et*4 + kl)*8 + nf)*64 + lane] = u;
  }
}

// ---- prep: qtf = bf16(q) in GEMM2 B-fragment-major layout ----
__global__ __launch_bounds__(256) void k_prep_qt(const float* __restrict__ q,
                                                 unsigned char* __restrict__ wsp){
  const int b = blockIdx.x >> 2, et = blockIdx.x & 3, e0 = et*128;
  __shared__ u16 tile[128*136];
  const int tid = threadIdx.x;
  #pragma unroll
  for (int i=0;i<16;i++){
    int id = tid + i*256;
    int qi = id >> 5;
    int el = (id & 31) << 2;
    float4 v = *(const float4*)(q + (size_t)(b*QQ+qi)*EE + e0 + el);
    ushort4 u; u.x = bfc(v.x); u.y = bfc(v.y); u.z = bfc(v.z); u.w = bfc(v.w);
    *(ushort4*)&tile[qi*136 + el] = u;
  }
  __syncthreads();
  const int lane = tid & 63, wv = tid >> 6, l15 = lane & 15, l4 = lane >> 4;
  uint4* qtf = (uint4*)(wsp + QTF_OFF);
  #pragma unroll
  for (int i=0;i<8;i++){
    int f = wv*8 + i;
    int ks2 = f >> 3, nl = f & 7, ne = et*8 + nl;
    uint32 x[4];
    #pragma unroll
    for (int p=0;p<4;p++){
      u16 t0 = tile[(ks2*32 + l4*8 + 2*p    )*136 + nl*16 + l15];
      u16 t1 = tile[(ks2*32 + l4*8 + 2*p + 1)*136 + nl*16 + l15];
      x[p] = (uint32)t0 | ((uint32)t1 << 16);
    }
    uint4 u; u.x = x[0]; u.y = x[1]; u.z = x[2]; u.w = x[3];
    qtf[(size_t)((b*4 + ks2)*32 + ne)*64 + lane] = u;
  }
}

// ---- prep: qdot[row] = q[row] . ws_q (exact f32) ----
__global__ __launch_bounds__(256) void k_prep_qd(const float* __restrict__ q,
                                                 const float* __restrict__ ws,
                                                 unsigned char* __restrict__ wsp){
  const int row = blockIdx.x*4 + (threadIdx.x >> 6);
  const int lane = threadIdx.x & 63;
  const float4* qr = (const float4*)(q + (size_t)row*EE) + lane*2;
  const float4* wq = (const float4*)ws + lane*2;
  float4 v0 = qr[0], v1 = qr[1], a0 = wq[0], a1 = wq[1];
  float dot = v0.x*a0.x + v0.y*a0.y + v0.z*a0.z + v0.w*a0.w
            + v1.x*a1.x + v1.y*a1.y + v1.z*a1.z + v1.w*a1.w;
  #pragma unroll
  for (int off=1; off<64; off<<=1) dot += __shfl_xor(dot, off);
  if (lane == 0) ((float*)(wsp + QD_OFF))[row] = dot;
}

// ---- main: 512 blocks x 8 waves; block = 64 ctx rows, full q=128.
// FLIPPED GEMM1: wave pins qm'-frags (16 q-rows, 64 VGPR) as MFMA-A; ctx tile
// streams from LDS as MFMA-B -> zero per-wave global B-traffic. sim^T softmax
// with m=0 exp (shift-invariant; max only for q2c, computed late). GEMM2 B
// (qtf bf16) DMA'd into dead tile region, double-buffered 16KB eighths.
__global__ __attribute__((amdgpu_flat_work_group_size(512, 512)))
           __attribute__((amdgpu_waves_per_eu(4, 4)))
void k_main(const float* __restrict__ ctx,
            unsigned char* __restrict__ wsp,
            float* __restrict__ out){
  __shared__ __align__(16) unsigned char tile[65536]; // bf16 [64][512] swizzled; [0:16K)=pfrag, [16K:48K)=qstage after GEMM1
  __shared__ __align__(16) float mx_s[64*8];
  __shared__ __align__(16) float sm_s[64*8];
  __shared__ float wrow_s[4][16];

  const int bid = blockIdx.x;
  const int sw  = (bid & 7)*64 + (bid >> 3);   // XCD-contiguous (512%8==0)
  const int b   = sw >> 4;
  const int t   = sw & 15;
  const int tid = threadIdx.x;
  const int lane = tid & 63;
  const int w    = tid >> 6;                   // 0..7: q-slice (GEMM1) / (rg,eh) (GEMM2)
  const int l15  = lane & 15;
  const int l4   = lane >> 4;
  const int rg   = w >> 1;
  const int eh   = w & 1;

  // ---- phase 1: stage ctx tile (64 rows x 512 f32) -> bf16 LDS, 16 coalesced loads ----
  const float4* cb4 = (const float4*)(ctx + (size_t)(b*CC + t*64)*EE);
  {
    float4 v[16];
    #pragma unroll
    for (int i=0;i<16;i++) v[i] = cb4[i*512 + tid];
    const int colb = (tid & 127)*8;
    #pragma unroll
    for (int i=0;i<16;i++){
      int row = i*4 + (tid >> 7);
      uint2 u;
      u.x = (uint32)bfc(v[i].x) | ((uint32)bfc(v[i].y) << 16);
      u.y = (uint32)bfc(v[i].z) | ((uint32)bfc(v[i].w) << 16);
      *(uint2*)(tile + row*1024 + (colb ^ ((row & 7) << 4))) = u;
    }
  }
  // qm' A-frags for this wave's 16 q-rows (issued after staging regs die; L2-hot)
  const uint4* qmf4 = (const uint4*)(wsp + QMF_OFF);
  bf16x8 a[16];
  #pragma unroll
  for (int ks=0; ks<16; ks++)
    a[ks] = __builtin_bit_cast(bf16x8, qmf4[(size_t)((b*16 + ks)*8 + w)*64 + lane]);
  const float4 qdv = *(const float4*)((const float*)(wsp + QD_OFF) + b*QQ + w*16 + l4*4);
  __syncthreads();                             // barrier0: tile ready

  // ---- GEMM1 (flipped): D[q16][c16] per c-chunk; A=regs, B=tile LDS ----
  f32x4 acc[4];
  #pragma unroll
  for (int cc=0;cc<4;cc++) acc[cc] = (f32x4){0.f,0.f,0.f,0.f};
  #pragma unroll
  for (int ks=0; ks<16; ks++){
    #pragma unroll
    for (int cc=0; cc<4; cc++){
      const int row = cc*16 + l15;
      bf16x8 bf = __builtin_bit_cast(bf16x8,
        *(const uint4*)(tile + row*1024 + ((ks*64 + l4*16) ^ ((row & 7) << 4))));
      acc[cc] = __builtin_amdgcn_mfma_f32_16x16x32_bf16(a[ks], bf, acc[cc], 0, 0, 0);
    }
  }
  __syncthreads();                             // barrier1: all tile reads done

  // ---- softmax on sim^T: lane owns q = w*16 + l4*4 + r for c = cc*16 + l15 ----
  // m=0 exp (exact: softmax shift-invariant; |v|<~15 here, clamp 80 for safety)
  {
    float pm[4], ps[4];
    #pragma unroll
    for (int cc=0; cc<4; cc++){
      float m = -3.0e38f, s = 0.f;
      u16 hb[4];
      #pragma unroll
      for (int r=0;r<4;r++){
        float vv = acc[cc][r] + qdv[r];
        vv = fminf(vv, 80.f);
        m = fmaxf(m, vv);
        u16 h = bfc(__expf(vv));
        hb[r] = h;
        s += bf2f(h);                          // denom over bf16-rounded p
      }
      // write P into GEMM2-A-frag layout: frag=(cc*4 + w>>1), L=((w&1)*2+(l4>>1))*16+l15, j0=(l4&1)*4
      uint2 u; u.x = (uint32)hb[0] | ((uint32)hb[1]<<16);
               u.y = (uint32)hb[2] | ((uint32)hb[3]<<16);
      *(uint2*)(tile + (cc*4 + (w>>1))*1024 + (((w&1)*2 + (l4>>1))*16 + l15)*16 + (l4&1)*8) = u;
      m = fmaxf(m, __shfl_xor(m, 16)); m = fmaxf(m, __shfl_xor(m, 32));
      s += __shfl_xor(s, 16);          s += __shfl_xor(s, 32);
      pm[cc] = m; ps[cc] = s;
    }
    if (l4 == 0){
      #pragma unroll
      for (int cc=0; cc<4; cc++){
        mx_s[(cc*16 + l15)*8 + w] = pm[cc];
        sm_s[(cc*16 + l15)*8 + w] = ps[cc];
      }
    }
  }
  __syncthreads();                             // barrier2: pfrag + per-wave stats ready

  // rden for this wave's GEMM2 c-rows (c = rg*16 + l4*4 + r)
  float rden[4];
  #pragma unroll
  for (int r=0;r<4;r++){
    const int c = rg*16 + l4*4 + r;
    f32x4 s0 = *(const f32x4*)&sm_s[c*8];
    f32x4 s1 = *(const f32x4*)&sm_s[c*8 + 4];
    rden[r] = 1.f/(s0[0]+s0[1]+s0[2]+s0[3]+s1[0]+s1[1]+s1[2]+s1[3]);
  }

  // q2c stats per 16-row group (eh==0 waves), true max over q from mx_s
  if (eh == 0){
    float mf[4];
    #pragma unroll
    for (int r=0;r<4;r++){
      const int c = rg*16 + l4*4 + r;
      f32x4 m0 = *(const f32x4*)&mx_s[c*8];
      f32x4 m1 = *(const f32x4*)&mx_s[c*8 + 4];
      mf[r] = fmaxf(fmaxf(fmaxf(m0[0],m0[1]), fmaxf(m0[2],m0[3])),
                    fmaxf(fmaxf(m1[0],m1[1]), fmaxf(m1[2],m1[3])));
    }
    float m16 = fmaxf(fmaxf(mf[0],mf[1]), fmaxf(mf[2],mf[3]));
    m16 = fmaxf(m16, __shfl_xor(m16, 16));
    m16 = fmaxf(m16, __shfl_xor(m16, 32));
    float wr[4], s16 = 0.f;
    #pragma unroll
    for (int r=0;r<4;r++){ wr[r] = __expf(mf[r] - m16); s16 += wr[r]; }
    s16 += __shfl_xor(s16, 16);
    s16 += __shfl_xor(s16, 32);
    if (l15 == 0){
      #pragma unroll
      for (int r=0;r<4;r++) wrow_s[rg][l4*4 + r] = wr[r];
    }
    if (lane == 0){
      ((float*)(wsp + MT_OFF))[b*64 + t*4 + rg] = m16;
      ((float*)(wsp + ST_OFF))[b*64 + t*4 + rg] = s16;
    }
  }

  // GEMM2 A-frags (P) from pfrag
  bf16x8 pa[4];
  #pragma unroll
  for (int k2=0;k2<4;k2++)
    pa[k2] = __builtin_bit_cast(bf16x8, *(const uint4*)(tile + (rg*4 + k2)*1024 + lane*16));

  // qtf DMA machinery: 8 e-eighth passes, double-buffered 16KB in dead tile region
  unsigned char* qstage = tile + 16384;
  const unsigned char* qtfb = wsp + QTF_OFF + (size_t)b*131072;
  auto dma = [&](int p){
    #pragma unroll
    for (int j=0;j<2;j++){
      const int f = w*2 + j;                   // 16 frags/pass across 8 waves
      const int ks2 = f >> 2, nl = f & 3;
      const unsigned char* g = qtfb + (size_t)(ks2*32 + p*4 + nl)*1024 + lane*16;
      __builtin_amdgcn_global_load_lds(
        (const __attribute__((address_space(1))) uint32*)g,
        (__attribute__((address_space(3))) uint32*)(qstage + (p&1)*16384 + f*1024),
        16, 0, 0);
    }
  };
  dma(0);
  __syncthreads();                             // barrier3: drains dma(0)

  // ---- GEMM2: c2q rows (rg*16..+15) x e (p*64 + eh*32 + 0..31) per pass ----
  float* ob = out + (size_t)(b*CC + t*64 + rg*16)*EE;
  #pragma unroll
  for (int p=0; p<8; p++){
    if (p < 7) dma(p+1);
    const unsigned char* qs = qstage + (p&1)*16384;
    f32x4 ac0 = (f32x4){0.f,0.f,0.f,0.f};
    f32x4 ac1 = (f32x4){0.f,0.f,0.f,0.f};
    #pragma unroll
    for (int k2=0;k2<4;k2++){
      bf16x8 b0 = __builtin_bit_cast(bf16x8, *(const uint4*)(qs + (k2*4 + eh*2 + 0)*1024 + lane*16));
      bf16x8 b1 = __builtin_bit_cast(bf16x8, *(const uint4*)(qs + (k2*4 + eh*2 + 1)*1024 + lane*16));
      ac0 = __builtin_amdgcn_mfma_f32_16x16x32_bf16(pa[k2], b0, ac0, 0, 0, 0);
      ac1 = __builtin_amdgcn_mfma_f32_16x16x32_bf16(pa[k2], b1, ac1, 0, 0, 0);
    }
    #pragma unroll
    for (int r=0;r<4;r++){
      ob[(size_t)(l4*4 + r)*EE + p*64 + eh*32 +  0 + l15] = ac0[r]*rden[r];
      ob[(size_t)(l4*4 + r)*EE + p*64 + eh*32 + 16 + l15] = ac1[r]*rden[r];
    }
    __syncthreads();                           // next pass's DMA landed; buffer safe to flip
  }

  // ---- fused q2c partial: rows rg*16..+15 x e-half eh (L2-hot re-read) ----
  {
    const float4* cq = (const float4*)(ctx + (size_t)(b*CC + t*64 + rg*16)*EE + eh*256) + lane;
    float4 a4; a4.x = 0.f; a4.y = 0.f; a4.z = 0.f; a4.w = 0.f;
    #pragma unroll
    for (int rr=0; rr<16; rr++){
      float wv = wrow_s[rg][rr];
      float4 g = cq[(size_t)rr*128];
      a4.x = fmaf(wv, g.x, a4.x); a4.y = fmaf(wv, g.y, a4.y);
      a4.z = fmaf(wv, g.z, a4.z); a4.w = fmaf(wv, g.w, a4.w);
    }
    float* pv = (float*)(wsp + PV_OFF) + (size_t)(b*64 + t*4 + rg)*EE + eh*256 + lane*4;
    *(float4*)pv = a4;
  }
}

// ---- q2c combine: 64 group-partials per batch ----
__global__ __launch_bounds__(256) void k_fin(unsigned char* __restrict__ wsp,
                                             float* __restrict__ out){
  const int b = blockIdx.x;
  __shared__ float sc_s[64];
  const int tid = threadIdx.x;
  if (tid < 64){
    float Mg = ((const float*)(wsp + MT_OFF))[b*64 + tid];
    float Sg = ((const float*)(wsp + ST_OFF))[b*64 + tid];
    float M = Mg;
    #pragma unroll
    for (int off=1; off<64; off<<=1) M = fmaxf(M, __shfl_xor(M, off));
    float ev = __expf(Mg - M);
    float ds = ev * Sg;
    #pragma unroll
    for (int off=1; off<64; off<<=1) ds += __shfl_xor(ds, off);
    sc_s[tid] = ev / ds;
  }
  __syncthreads();
  const float* pv = (const float*)(wsp + PV_OFF) + (size_t)b*64*EE;
  float a0 = 0.f, a1 = 0.f;
  #pragma unroll 8
  for (int g=0; g<64; g++){
    float s = sc_s[g];
    a0 = fmaf(s, pv[g*EE + tid],       a0);
    a1 = fmaf(s, pv[g*EE + tid + 256], a1);
  }
  size_t base = (size_t)BB*CC*EE + (size_t)b*EE;
  out[base + tid]       = a0;
  out[base + tid + 256] = a1;
}

extern "C" void kernel_launch(void* const* d_in, const int* in_sizes, int n_in,
                              void* d_out, int out_size, void* d_ws, size_t ws_size,
                              hipStream_t stream){
  const float* ctx = (const float*)d_in[0];
  const float* q   = (const float*)d_in[1];
  const float* ws  = (const float*)d_in[2];
  float* out = (float*)d_out;
  unsigned char* wsp = (unsigned char*)d_ws;

  k_prep_qm<<<dim3(BB*4),    dim3(256), 0, stream>>>(q, ws, wsp);
  k_prep_qt<<<dim3(BB*4),    dim3(256), 0, stream>>>(q, wsp);
  k_prep_qd<<<dim3(BB*QQ/4), dim3(256), 0, stream>>>(q, ws, wsp);
  k_main   <<<dim3(512),     dim3(512), 0, stream>>>(ctx, wsp, out);
  k_fin    <<<dim3(BB),      dim3(256), 0, stream>>>(wsp, out);
}